// Round 1
// baseline (537.410 us; speedup 1.0000x reference)
//
#include <hip/hip_runtime.h>
#include <hip/hip_bf16.h>

#define NFEAT 128
#define HID 256
#define BN_EPS 1e-5f

typedef __attribute__((ext_vector_type(8))) __bf16 bf16x8;
typedef __attribute__((ext_vector_type(4))) float f32x4;

static __device__ __forceinline__ float bflo(unsigned u) {
    union { unsigned x; float f; } c; c.x = u << 16; return c.f;
}
static __device__ __forceinline__ float bfhi(unsigned u) {
    union { unsigned x; float f; } c; c.x = u & 0xffff0000u; return c.f;
}

// ---------- CSR build ----------
__global__ void k_count(const int* __restrict__ ei, int E, int* __restrict__ cnt,
                        int* __restrict__ rank) {
    int e = blockIdx.x * blockDim.x + threadIdx.x;
    if (e < E) rank[e] = atomicAdd(&cnt[ei[E + e]], 1);
}

__global__ void k_scan1(const int* __restrict__ cnt, int n, int* __restrict__ partial,
                        int* __restrict__ blk_total) {
    __shared__ int sh[256];
    int i = blockIdx.x * 256 + threadIdx.x;
    int v = (i < n) ? cnt[i] : 0;
    sh[threadIdx.x] = v;
    __syncthreads();
    for (int off = 1; off < 256; off <<= 1) {
        int x = (threadIdx.x >= off) ? sh[threadIdx.x - off] : 0;
        __syncthreads();
        sh[threadIdx.x] += x;
        __syncthreads();
    }
    if (i < n) partial[i] = sh[threadIdx.x] - v;
    if (threadIdx.x == 255) blk_total[blockIdx.x] = sh[255];
}

__global__ void k_scan2(int* __restrict__ blk, int nb) {
    __shared__ int sh[256];
    int t = threadIdx.x;
    int v = (t < nb) ? blk[t] : 0;
    sh[t] = v;
    __syncthreads();
    for (int off = 1; off < 256; off <<= 1) {
        int x = (t >= off) ? sh[t - off] : 0;
        __syncthreads();
        sh[t] += x;
        __syncthreads();
    }
    if (t < nb) blk[t] = sh[t] - v;
}

__global__ void k_finalize(const int* __restrict__ partial, const int* __restrict__ blk,
                           const int* __restrict__ cnt, int n, int* __restrict__ row_start,
                           float* __restrict__ dinv) {
    int i = blockIdx.x * blockDim.x + threadIdx.x;
    if (i < n) {
        row_start[i] = partial[i] + blk[i >> 8];
        dinv[i] = rsqrtf((float)(cnt[i] + 1));
    }
}

__global__ void k_fill(const int* __restrict__ ei, const int* __restrict__ rank,
                       const int* __restrict__ row_start, int E, int* __restrict__ col) {
    int e = blockIdx.x * blockDim.x + threadIdx.x;
    if (e < E) {
        int d = ei[E + e];
        col[row_start[d] + rank[e]] = ei[e];
    }
}

// ---------- fp32 -> bf16 cast with per-row dinv scale ----------
__global__ void k_scale_cast(const float* __restrict__ in, const float* __restrict__ dinv,
                             __hip_bfloat16* __restrict__ out, int shift, int n4) {
    int i = blockIdx.x * blockDim.x + threadIdx.x;
    if (i < n4) {
        float d = dinv[i >> shift];
        float4 v = *(const float4*)(in + (size_t)i * 4);
        __hip_bfloat16* o = out + (size_t)i * 4;
        o[0] = __float2bfloat16(v.x * d);
        o[1] = __float2bfloat16(v.y * d);
        o[2] = __float2bfloat16(v.z * d);
        o[3] = __float2bfloat16(v.w * d);
    }
}

// ---------- all 3 weight transposes in one dispatch ----------
__global__ void k_transpose3(const float* __restrict__ W1, const float* __restrict__ W2,
                             const float* __restrict__ Wf, __hip_bfloat16* __restrict__ Wt1,
                             __hip_bfloat16* __restrict__ Wt2, __hip_bfloat16* __restrict__ Wtf) {
    int idx = blockIdx.x * 256 + threadIdx.x;
    const float* W;
    __hip_bfloat16* Wt;
    int K, base;
    if (idx < 32768) { W = W1; Wt = Wt1; K = 128; base = idx; }
    else if (idx < 98304) { W = W2; Wt = Wt2; K = 256; base = idx - 32768; }
    else { W = Wf; Wt = Wtf; K = 256; base = idx - 98304; }
    int n = base & 255;
    int k = base >> 8;
    if (k < K) Wt[n * K + k] = __float2bfloat16(W[k * 256 + n]);
}

// ---------- XCD-sliced SpMM on pre-scaled rows ----------
// Feature dim split into 8 slices; slice = blockIdx.x & 7 so each XCD (round-robin
// dispatch) gathers only from its 1/8 column-slice of Hs: working set N*C/8*2B
// (3.2 MB @ C=256, 1.6 MB @ C=128) fits the per-XCD 4 MB L2 -> gathers become L2 hits.
// Lane layout: LPE lanes per edge (4 ch each, 8B loads), EG = 64/LPE edges in flight.
// Cross-lane shfl_xor tree reduces the EG edge-groups; lanes with eg==0 write 4 ch.
template <int C, int NPW>
__global__ __launch_bounds__(256) void k_spmm_sl(const __hip_bfloat16* __restrict__ Hs,
                                                 const int* __restrict__ rs,
                                                 const int* __restrict__ rc,
                                                 const int* __restrict__ col,
                                                 const float* __restrict__ dinv,
                                                 __hip_bfloat16* __restrict__ out, int N) {
    constexpr int S = C / 8;      // channels per slice
    constexpr int LPE = S / 4;    // lanes per edge (4 channels / lane)
    constexpr int EG = 64 / LPE;  // edges concurrently in flight per wave
    const int slice = blockIdx.x & 7;
    const int lane = threadIdx.x & 63;
    const int wv = threadIdx.x >> 6;
    const int eg = lane / LPE;
    const int cp = lane % LPE;
    const int choff = slice * S + cp * 4;  // element offset within a row
    const int nbase = (blockIdx.x >> 3) * (4 * NPW) + wv * NPW;

    for (int n = 0; n < NPW; n++) {
        const int node = nbase + n;
        if (node >= N) return;  // nodes are monotone; no barriers in kernel
        const int s = rs[node];
        const int deg = rc[node];
        const float di = dinv[node];

        float a0 = 0.f, a1 = 0.f, a2 = 0.f, a3 = 0.f;
        if (eg == 0) {  // self-loop term
            uint2 u = *(const uint2*)(Hs + (size_t)node * C + choff);
            a0 = bflo(u.x); a1 = bfhi(u.x); a2 = bflo(u.y); a3 = bfhi(u.y);
        }
        int e = eg;
        int idx = (e < deg) ? col[s + e] : 0;
        while (e < deg) {
            int e2 = e + EG;
            int idx2 = (e2 < deg) ? col[s + e2] : 0;  // prefetch next idx
            uint2 u = *(const uint2*)(Hs + (size_t)idx * C + choff);
            a0 += bflo(u.x); a1 += bfhi(u.x); a2 += bflo(u.y); a3 += bfhi(u.y);
            e = e2;
            idx = idx2;
        }
#pragma unroll
        for (int m = LPE; m < 64; m <<= 1) {
            a0 += __shfl_xor(a0, m);
            a1 += __shfl_xor(a1, m);
            a2 += __shfl_xor(a2, m);
            a3 += __shfl_xor(a3, m);
        }
        if (eg == 0) {
            union { unsigned w[2]; unsigned short us[4]; } o;
            __hip_bfloat16 b0 = __float2bfloat16(di * a0); o.us[0] = *(unsigned short*)&b0;
            __hip_bfloat16 b1 = __float2bfloat16(di * a1); o.us[1] = *(unsigned short*)&b1;
            __hip_bfloat16 b2 = __float2bfloat16(di * a2); o.us[2] = *(unsigned short*)&b2;
            __hip_bfloat16 b3 = __float2bfloat16(di * a3); o.us[3] = *(unsigned short*)&b3;
            *(uint2*)(out + (size_t)node * C + choff) = *(uint2*)o.w;
        }
    }
}

// ---------- single-barrier MFMA GEMM ----------
// out[M][256] = A[M][K] @ B[K][256] + bias.  Block = 64 rows x 128 cols, grid (M/64, 2).
// B slice (128 cols x K) staged to LDS ONCE (all loads in flight, one barrier).
// A fragments load DIRECTLY global->VGPR (A-operand layout A[m=lane&15][k=quad*8+j] is a
// contiguous 16B row chunk) — no second barrier, no per-iteration sync.
// outb mode: bf16 out + fused BN stats; outf mode: fp32 out.
// NOTE: last block reads A rows >= M (stays inside d_ws; results discarded by store guard).
template <int K>
__global__ __launch_bounds__(256) void k_gemm2(const __hip_bfloat16* __restrict__ A,
                                               const __hip_bfloat16* __restrict__ Bt,
                                               const float* __restrict__ bias,
                                               __hip_bfloat16* __restrict__ outb,
                                               float* __restrict__ outf,
                                               float* __restrict__ gsum, float* __restrict__ gsq,
                                               int M) {
    constexpr int KS = K / 32;       // MFMA k-steps
    constexpr int LDR = K + 8;       // LDS row stride (elems): +16B pad -> <=2-way read alias
    constexpr int ROWU4 = K / 8;     // uint4 per B row
    __shared__ __align__(16) unsigned short Bs[128 * LDR];
    __shared__ float sred[4][128];
    __shared__ float qred[4][128];

    const int t = threadIdx.x;
    const int wv = t >> 6;
    const int lane = t & 63;
    const int mlane = lane & 15;
    const int quad = lane >> 4;
    const int m0 = blockIdx.x * 64;
    const int n0 = blockIdx.y * 128;

    // A fragments: wave wv covers rows m0+wv*16 .. +15; lane's operand row = m0+wv*16+mlane
    const int arow = m0 + wv * 16 + mlane;
    bf16x8 a[KS];
#pragma unroll
    for (int ks = 0; ks < KS; ks++)
        a[ks] = *(const bf16x8*)(A + (size_t)arow * K + ks * 32 + quad * 8);

    // stage B slice: Bt[n0..n0+128][0..K] -> Bs (coalesced, all 16B loads in flight)
#pragma unroll
    for (int i = 0; i < 128 * ROWU4 / 256; i++) {
        int idx = t + i * 256;
        int row = idx / ROWU4;
        int c = idx % ROWU4;
        uint4 v = *(const uint4*)(Bt + (size_t)(n0 + row) * K + c * 8);
        *(uint4*)(Bs + row * LDR + c * 8) = v;
    }
    __syncthreads();  // the ONLY barrier before the epilogue

    f32x4 acc[8];
#pragma unroll
    for (int i = 0; i < 8; i++) acc[i] = (f32x4){0.f, 0.f, 0.f, 0.f};

#pragma unroll
    for (int nt = 0; nt < 8; nt++) {
        const unsigned short* bp = Bs + (nt * 16 + mlane) * LDR + quad * 8;
#pragma unroll
        for (int ks = 0; ks < KS; ks++) {
            bf16x8 b = *(const bf16x8*)(bp + ks * 32);
            acc[nt] = __builtin_amdgcn_mfma_f32_16x16x32_bf16(a[ks], b, acc[nt], 0, 0, 0);
        }
    }

    // C/D mapping: col = lane&15, row = quad*4 + reg
    if (outb) {
        float sp[8], qp[8];
#pragma unroll
        for (int nt = 0; nt < 8; nt++) {
            int colx = n0 + nt * 16 + mlane;
            float bv = bias[colx];
            float s = 0.f, q = 0.f;
#pragma unroll
            for (int r = 0; r < 4; r++) {
                int row = m0 + wv * 16 + quad * 4 + r;
                if (row < M) {
                    float h = acc[nt][r] + bv;
                    outb[(size_t)row * HID + colx] = __float2bfloat16(h);
                    s += h;
                    q += h * h;
                }
            }
            sp[nt] = s;
            qp[nt] = q;
        }
#pragma unroll
        for (int nt = 0; nt < 8; nt++) {
            sp[nt] += __shfl_xor(sp[nt], 16);
            sp[nt] += __shfl_xor(sp[nt], 32);
            qp[nt] += __shfl_xor(qp[nt], 16);
            qp[nt] += __shfl_xor(qp[nt], 32);
        }
        if (quad == 0) {
#pragma unroll
            for (int nt = 0; nt < 8; nt++) {
                sred[wv][nt * 16 + mlane] = sp[nt];
                qred[wv][nt * 16 + mlane] = qp[nt];
            }
        }
        __syncthreads();
        if (t < 128) {
            float ss = sred[0][t] + sred[1][t] + sred[2][t] + sred[3][t];
            float qq = qred[0][t] + qred[1][t] + qred[2][t] + qred[3][t];
            atomicAdd(&gsum[n0 + t], ss);
            atomicAdd(&gsq[n0 + t], qq);
        }
    } else {
#pragma unroll
        for (int nt = 0; nt < 8; nt++) {
            int colx = n0 + nt * 16 + mlane;
            float bv = bias[colx];
#pragma unroll
            for (int r = 0; r < 4; r++) {
                int row = m0 + wv * 16 + quad * 4 + r;
                if (row < M) outf[(size_t)row * HID + colx] = acc[nt][r] + bv;
            }
        }
    }
}

// ---------- BN normalize, bf16 in -> bf16 out, optional per-row dinv scale ----------
__global__ __launch_bounds__(256) void k_bnnorm(const __hip_bfloat16* __restrict__ in,
                                                const float* __restrict__ gsum,
                                                const float* __restrict__ gsq,
                                                const float* __restrict__ g,
                                                const float* __restrict__ be,
                                                const float* __restrict__ dinv, float invN,
                                                __hip_bfloat16* __restrict__ out, int n4) {
    int idx = blockIdx.x * blockDim.x + threadIdx.x;
    if (idx < n4) {
        int cbase = (idx * 4) & (HID - 1);
        int row = (idx * 4) >> 8;
        float rowsc = dinv ? dinv[row] : 1.0f;
        uint2 u = *(const uint2*)(in + (size_t)idx * 4);
        float v[4] = {bflo(u.x), bfhi(u.x), bflo(u.y), bfhi(u.y)};
        union { unsigned w[2]; unsigned short us[4]; } o;
#pragma unroll
        for (int i = 0; i < 4; i++) {
            int c = cbase + i;
            float mean = gsum[c] * invN;
            float var = gsq[c] * invN - mean * mean;
            float sc = rsqrtf(var + BN_EPS) * g[c];
            __hip_bfloat16 b = __float2bfloat16(((v[i] - mean) * sc + be[c]) * rowsc);
            o.us[i] = *(unsigned short*)&b;
        }
        *(uint2*)(out + (size_t)idx * 4) = *(uint2*)o.w;
    }
}

extern "C" void kernel_launch(void* const* d_in, const int* in_sizes, int n_in, void* d_out,
                              int out_size, void* d_ws, size_t ws_size, hipStream_t stream) {
    const float* x = (const float*)d_in[0];
    const int* ei = (const int*)d_in[1];
    const float* W1 = (const float*)d_in[2];
    const float* b1 = (const float*)d_in[3];
    const float* g1 = (const float*)d_in[4];
    const float* be1 = (const float*)d_in[5];
    const float* W2 = (const float*)d_in[6];
    const float* b2 = (const float*)d_in[7];
    const float* g2 = (const float*)d_in[8];
    const float* be2 = (const float*)d_in[9];
    const float* Wfc = (const float*)d_in[10];
    const float* bfc = (const float*)d_in[11];
    float* out = (float*)d_out;

    const int N = in_sizes[0] / NFEAT;  // 50000
    const int E = in_sizes[1] / 2;      // 800000
    const float invN = 1.0f / (float)N;

    char* ws = (char*)d_ws;
    size_t off = 0;
    auto alloc = [&](size_t bytes) -> void* {
        void* p = ws + off;
        off += (bytes + 255) & ~(size_t)255;
        return p;
    };
    int* row_cnt = (int*)alloc((size_t)N * 4);
    int* partial = (int*)alloc((size_t)N * 4);
    int* row_start = (int*)alloc((size_t)N * 4);
    int* blk = (int*)alloc(256 * 4);
    float* dinv = (float*)alloc((size_t)N * 4);
    int* rank = (int*)alloc((size_t)E * 4);
    int* col_idx = (int*)alloc((size_t)E * 4);
    float* gs1 = (float*)alloc(512 * 4);
    float* gs2 = (float*)alloc(512 * 4);
    __hip_bfloat16* Wt1 = (__hip_bfloat16*)alloc(256 * 128 * 2);
    __hip_bfloat16* Wt2 = (__hip_bfloat16*)alloc(256 * 256 * 2);
    __hip_bfloat16* Wtf = (__hip_bfloat16*)alloc(256 * 256 * 2);
    // xs (N x128) + aggX (N x128) contiguous; both dead after gemm1 -> agg2 reuses.
    __hip_bfloat16* xs = (__hip_bfloat16*)alloc((size_t)N * NFEAT * 2 * 2);
    __hip_bfloat16* aggX = xs + (size_t)N * NFEAT;
    __hip_bfloat16* agg2 = xs;
    __hip_bfloat16* h1 = (__hip_bfloat16*)alloc((size_t)N * HID * 2);
    __hip_bfloat16* h2 = (__hip_bfloat16*)alloc((size_t)N * HID * 2);
    __hip_bfloat16* bufB = h1;  // bn2 out (h1 dead by then)

    hipMemsetAsync(row_cnt, 0, (size_t)N * 4, stream);
    hipMemsetAsync(gs1, 0, 1024 * 4, stream);

    // CSR build
    k_count<<<(E + 255) / 256, 256, 0, stream>>>(ei, E, row_cnt, rank);
    int nblk = (N + 255) / 256;
    k_scan1<<<nblk, 256, 0, stream>>>(row_cnt, N, partial, blk);
    k_scan2<<<1, 256, 0, stream>>>(blk, nblk);
    k_finalize<<<nblk, 256, 0, stream>>>(partial, blk, row_cnt, N, row_start, dinv);
    k_fill<<<(E + 255) / 256, 256, 0, stream>>>(ei, rank, row_start, E, col_idx);

    k_transpose3<<<640, 256, 0, stream>>>(W1, W2, Wfc, Wt1, Wt2, Wtf);

    // xs = dinv_row * x (bf16); shift = log2(128/4) = 5
    k_scale_cast<<<(N * NFEAT / 4 + 255) / 256, 256, 0, stream>>>(x, dinv, xs, 5, N * NFEAT / 4);

    dim3 gg((N + 63) / 64, 2);
    constexpr int NPW = 8;                       // nodes per wave in sliced SpMM
    int chunks = (N + 4 * NPW - 1) / (4 * NPW);  // 4 waves/block
    int sgrid = 8 * chunks;                      // 8 channel-slices -> 8 XCDs

    // Layer 1: aggregate (128ch, XCD-sliced) -> GEMM (+bias, fused stats)
    k_spmm_sl<NFEAT, NPW><<<sgrid, 256, 0, stream>>>(xs, row_start, row_cnt, col_idx, dinv, aggX, N);
    k_gemm2<NFEAT><<<gg, 256, 0, stream>>>(aggX, Wt1, b1, h1, nullptr, gs1, gs1 + 256, N);
    // BN1 (+dinv pre-scale, in place) -> Layer 2 aggregate -> GEMM
    k_bnnorm<<<(N * HID / 4 + 255) / 256, 256, 0, stream>>>(h1, gs1, gs1 + 256, g1, be1, dinv,
                                                            invN, h1, N * HID / 4);
    k_spmm_sl<HID, NPW><<<sgrid, 256, 0, stream>>>(h1, row_start, row_cnt, col_idx, dinv, agg2, N);
    k_gemm2<HID><<<gg, 256, 0, stream>>>(agg2, Wt2, b2, h2, nullptr, gs2, gs2 + 256, N);
    // BN2 -> final linear (fp32 out)
    k_bnnorm<<<(N * HID / 4 + 255) / 256, 256, 0, stream>>>(h2, gs2, gs2 + 256, g2, be2, nullptr,
                                                            invN, bufB, N * HID / 4);
    k_gemm2<HID><<<gg, 256, 0, stream>>>(bufB, Wtf, bfc, nullptr, out, nullptr, nullptr, N);
}

// Round 2
// 405.824 us; speedup vs baseline: 1.3242x; 1.3242x over previous
//
#include <hip/hip_runtime.h>
#include <hip/hip_bf16.h>

#define NFEAT 128
#define HID 256
#define BN_EPS 1e-5f

typedef __attribute__((ext_vector_type(8))) __bf16 bf16x8;
typedef __attribute__((ext_vector_type(4))) float f32x4;

static __device__ __forceinline__ float bflo(unsigned u) {
    union { unsigned x; float f; } c; c.x = u << 16; return c.f;
}
static __device__ __forceinline__ float bfhi(unsigned u) {
    union { unsigned x; float f; } c; c.x = u & 0xffff0000u; return c.f;
}

// ---------- CSR build ----------
__global__ void k_count(const int* __restrict__ ei, int E, int* __restrict__ cnt,
                        int* __restrict__ rank) {
    int e = blockIdx.x * blockDim.x + threadIdx.x;
    if (e < E) rank[e] = atomicAdd(&cnt[ei[E + e]], 1);
}

__global__ void k_scan1(const int* __restrict__ cnt, int n, int* __restrict__ partial,
                        int* __restrict__ blk_total) {
    __shared__ int sh[256];
    int i = blockIdx.x * 256 + threadIdx.x;
    int v = (i < n) ? cnt[i] : 0;
    sh[threadIdx.x] = v;
    __syncthreads();
    for (int off = 1; off < 256; off <<= 1) {
        int x = (threadIdx.x >= off) ? sh[threadIdx.x - off] : 0;
        __syncthreads();
        sh[threadIdx.x] += x;
        __syncthreads();
    }
    if (i < n) partial[i] = sh[threadIdx.x] - v;
    if (threadIdx.x == 255) blk_total[blockIdx.x] = sh[255];
}

__global__ void k_scan2(int* __restrict__ blk, int nb) {
    __shared__ int sh[256];
    int t = threadIdx.x;
    int v = (t < nb) ? blk[t] : 0;
    sh[t] = v;
    __syncthreads();
    for (int off = 1; off < 256; off <<= 1) {
        int x = (t >= off) ? sh[t - off] : 0;
        __syncthreads();
        sh[t] += x;
        __syncthreads();
    }
    if (t < nb) blk[t] = sh[t] - v;
}

__global__ void k_finalize(const int* __restrict__ partial, const int* __restrict__ blk,
                           const int* __restrict__ cnt, int n, int* __restrict__ row_start,
                           float* __restrict__ dinv) {
    int i = blockIdx.x * blockDim.x + threadIdx.x;
    if (i < n) {
        row_start[i] = partial[i] + blk[i >> 8];
        dinv[i] = rsqrtf((float)(cnt[i] + 1));
    }
}

__global__ void k_fill(const int* __restrict__ ei, const int* __restrict__ rank,
                       const int* __restrict__ row_start, int E, int* __restrict__ col) {
    int e = blockIdx.x * blockDim.x + threadIdx.x;
    if (e < E) {
        int d = ei[E + e];
        col[row_start[d] + rank[e]] = ei[e];
    }
}

// ---------- r = A_hat * 1  (r_i = dinv_i*(dinv_i + sum_j dinv_j)) ----------
__global__ __launch_bounds__(256) void k_rvec(const int* __restrict__ rs,
                                              const int* __restrict__ rc,
                                              const int* __restrict__ col,
                                              const float* __restrict__ dinv,
                                              float* __restrict__ r, int N) {
    const int wid = blockIdx.x * 4 + (threadIdx.x >> 6);
    if (wid >= N) return;
    const int lane = threadIdx.x & 63;
    const int s = rs[wid];
    const int deg = rc[wid];
    float acc = 0.f;
    for (int e = lane; e < deg; e += 64) acc += dinv[col[s + e]];
#pragma unroll
    for (int m = 1; m < 64; m <<= 1) acc += __shfl_xor(acc, m);
    if (lane == 0) {
        float di = dinv[wid];
        r[wid] = di * (di + acc);
    }
}

// ---------- fp32 -> bf16 cast with per-row dinv scale ----------
__global__ void k_scale_cast(const float* __restrict__ in, const float* __restrict__ dinv,
                             __hip_bfloat16* __restrict__ out, int shift, int n4) {
    int i = blockIdx.x * blockDim.x + threadIdx.x;
    if (i < n4) {
        float d = dinv[i >> shift];
        float4 v = *(const float4*)(in + (size_t)i * 4);
        __hip_bfloat16* o = out + (size_t)i * 4;
        o[0] = __float2bfloat16(v.x * d);
        o[1] = __float2bfloat16(v.y * d);
        o[2] = __float2bfloat16(v.z * d);
        o[3] = __float2bfloat16(v.w * d);
    }
}

// ---------- weight transposes (W1 -> Wt1 [256][128], Wfc -> Wtf [256][256]) ----------
__global__ void k_transpose2(const float* __restrict__ W1, const float* __restrict__ Wf,
                             __hip_bfloat16* __restrict__ Wt1, __hip_bfloat16* __restrict__ Wtf) {
    int idx = blockIdx.x * 256 + threadIdx.x;
    if (idx < 32768) {
        int n = idx & 255;           // out channel
        int k = idx >> 8;            // 0..127
        Wt1[n * 128 + k] = __float2bfloat16(W1[k * 256 + n]);
    } else {
        int base = idx - 32768;      // 0..65535
        int n = base & 255;
        int k = base >> 8;           // 0..255
        Wtf[n * 256 + k] = __float2bfloat16(Wf[k * 256 + n]);
    }
}

// ---------- BN affine fold: sc = g*rsqrt(var+eps); bv = (b - mean)*sc + be ----------
__global__ void k_bnfold(const float* __restrict__ gsum, const float* __restrict__ gsq,
                         const float* __restrict__ g, const float* __restrict__ be,
                         const float* __restrict__ b, float invN, float* __restrict__ sc,
                         float* __restrict__ bv) {
    int c = threadIdx.x;
    float mean = gsum[c] * invN;
    float var = gsq[c] * invN - mean * mean;
    float s = rsqrtf(var + BN_EPS) * g[c];
    float bb = b ? b[c] : 0.f;
    sc[c] = s;
    bv[c] = (bb - mean) * s + be[c];
}

// ---------- folded weight: WfT[n][k] = sum_m W1[k][m]*sc[m]*W2[m][n]  (Bt layout, bf16) ----------
__global__ __launch_bounds__(256) void k_foldW(const float* __restrict__ W1,
                                               const float* __restrict__ W2,
                                               const float* __restrict__ sc,
                                               __hip_bfloat16* __restrict__ WfT) {
    int k = blockIdx.x;    // 0..127
    int n = threadIdx.x;   // 0..255
    float acc = 0.f;
    for (int m = 0; m < 256; m++) acc += W1[k * 256 + m] * sc[m] * W2[m * 256 + n];
    WfT[(size_t)n * 128 + k] = __float2bfloat16(acc);
}

// ---------- u[n] = sum_m W2[m][n] * bv[m] ----------
__global__ void k_uvec(const float* __restrict__ W2, const float* __restrict__ bv,
                       float* __restrict__ u) {
    int n = threadIdx.x;
    float acc = 0.f;
    for (int m = 0; m < 256; m++) acc += W2[m * 256 + n] * bv[m];
    u[n] = acc;
}

// ---------- wave-per-node pure-add SpMM on pre-scaled rows (round-0 form + dual out) ----------
template <int PL>
static __device__ __forceinline__ void loadrow(const __hip_bfloat16* p, float* v) {
    if constexpr (PL == 4) {
        uint2 u = *(const uint2*)p;
        v[0] = bflo(u.x); v[1] = bfhi(u.x); v[2] = bflo(u.y); v[3] = bfhi(u.y);
    } else {
        unsigned u = *(const unsigned*)p;
        v[0] = bflo(u); v[1] = bfhi(u);
    }
}

template <int C>
__global__ __launch_bounds__(256) void k_spmm_w(const __hip_bfloat16* __restrict__ Hs,
                                                const int* __restrict__ rs,
                                                const int* __restrict__ rc,
                                                const int* __restrict__ col,
                                                const float* __restrict__ dinv,
                                                __hip_bfloat16* __restrict__ out,
                                                __hip_bfloat16* __restrict__ out2, int N) {
    constexpr int PL = C / 64;
    const int wid = blockIdx.x * 4 + (threadIdx.x >> 6);
    if (wid >= N) return;
    const int lane = threadIdx.x & 63;
    const int ch = lane * PL;
    const int s = rs[wid];
    const int deg = rc[wid];
    const float di = dinv[wid];

    float acc[PL];
    loadrow<PL>(Hs + (size_t)wid * C + ch, acc);  // self-loop term

    int e = 0;
    for (; e + 8 <= deg; e += 8) {
        int idx[8];
#pragma unroll
        for (int j = 0; j < 8; j++) idx[j] = col[s + e + j];
        float v[8][PL];
#pragma unroll
        for (int j = 0; j < 8; j++) loadrow<PL>(Hs + (size_t)idx[j] * C + ch, v[j]);
#pragma unroll
        for (int j = 0; j < 8; j++)
#pragma unroll
            for (int i = 0; i < PL; i++) acc[i] += v[j][i];
    }
    for (; e < deg; e++) {
        int i0 = col[s + e];
        float v0[PL];
        loadrow<PL>(Hs + (size_t)i0 * C + ch, v0);
#pragma unroll
        for (int i = 0; i < PL; i++) acc[i] += v0[i];
    }
    union { unsigned u[PL / 2]; unsigned short us[PL]; } o;
#pragma unroll
    for (int i = 0; i < PL; i++) {
        __hip_bfloat16 b = __float2bfloat16(di * acc[i]);
        o.us[i] = *(unsigned short*)&b;
    }
    if constexpr (PL == 4)
        *(uint2*)(out + (size_t)wid * C + ch) = *(uint2*)o.u;
    else
        *(unsigned*)(out + (size_t)wid * C + ch) = o.u[0];
    if (out2) {  // dinv-prescaled copy for the next aggregation pass
        union { unsigned u[PL / 2]; unsigned short us[PL]; } o2;
        float d2 = di * di;
#pragma unroll
        for (int i = 0; i < PL; i++) {
            __hip_bfloat16 b = __float2bfloat16(d2 * acc[i]);
            o2.us[i] = *(unsigned short*)&b;
        }
        if constexpr (PL == 4)
            *(uint2*)(out2 + (size_t)wid * C + ch) = *(uint2*)o2.u;
        else
            *(unsigned*)(out2 + (size_t)wid * C + ch) = o2.u[0];
    }
}

// ---------- single-barrier MFMA GEMM ----------
// out[M][256] = A[M][K] @ B[K][256] (+bias) (+ rank-1 rvec*uvec^T) ; optional BN affine on A;
// optional bf16/fp32 out; optional fused BN stats. Block = 64 rows x 128 cols, grid (M/64, 2).
// NOTE: last block reads A rows >= M (buffers padded; results discarded by store guard).
template <int K>
__global__ __launch_bounds__(256) void k_gemm2(const __hip_bfloat16* __restrict__ A,
                                               const __hip_bfloat16* __restrict__ Bt,
                                               const float* __restrict__ bias,
                                               __hip_bfloat16* __restrict__ outb,
                                               float* __restrict__ outf,
                                               float* __restrict__ gsum, float* __restrict__ gsq,
                                               const float* __restrict__ rvec,
                                               const float* __restrict__ uvec,
                                               const float* __restrict__ bnsc,
                                               const float* __restrict__ bnof, int M) {
    constexpr int KS = K / 32;       // MFMA k-steps
    constexpr int LDR = K + 8;       // LDS row stride (elems): +16B pad -> <=2-way read alias
    constexpr int ROWU4 = K / 8;     // uint4 per B row
    __shared__ __align__(16) unsigned short Bs[128 * LDR];
    __shared__ float sred[4][128];
    __shared__ float qred[4][128];

    const int t = threadIdx.x;
    const int wv = t >> 6;
    const int lane = t & 63;
    const int mlane = lane & 15;
    const int quad = lane >> 4;
    const int m0 = blockIdx.x * 64;
    const int n0 = blockIdx.y * 128;

    // A fragments: wave wv covers rows m0+wv*16 .. +15; lane's operand row = m0+wv*16+mlane
    const int arow = m0 + wv * 16 + mlane;
    bf16x8 a[KS];
#pragma unroll
    for (int ks = 0; ks < KS; ks++) {
        bf16x8 raw = *(const bf16x8*)(A + (size_t)arow * K + ks * 32 + quad * 8);
        if (bnsc) {  // BN affine applied in-register (pre-MFMA), channel = ks*32+quad*8+j
            int cb = ks * 32 + quad * 8;
            union { bf16x8 v; unsigned u[4]; } cu; cu.v = raw;
            union { unsigned u[4]; unsigned short us[8]; } ou;
#pragma unroll
            for (int j = 0; j < 4; j++) {
                float lo = bflo(cu.u[j]) * bnsc[cb + 2 * j] + bnof[cb + 2 * j];
                float hi = bfhi(cu.u[j]) * bnsc[cb + 2 * j + 1] + bnof[cb + 2 * j + 1];
                __hip_bfloat16 bl = __float2bfloat16(lo);
                __hip_bfloat16 bh = __float2bfloat16(hi);
                ou.us[2 * j] = *(unsigned short*)&bl;
                ou.us[2 * j + 1] = *(unsigned short*)&bh;
            }
            a[ks] = *(bf16x8*)ou.u;
        } else {
            a[ks] = raw;
        }
    }

    // stage B slice: Bt[n0..n0+128][0..K] -> Bs (coalesced, all 16B loads in flight)
#pragma unroll
    for (int i = 0; i < 128 * ROWU4 / 256; i++) {
        int idx = t + i * 256;
        int row = idx / ROWU4;
        int c = idx % ROWU4;
        uint4 v = *(const uint4*)(Bt + (size_t)(n0 + row) * K + c * 8);
        *(uint4*)(Bs + row * LDR + c * 8) = v;
    }
    __syncthreads();  // the ONLY barrier before the epilogue

    f32x4 acc[8];
#pragma unroll
    for (int i = 0; i < 8; i++) acc[i] = (f32x4){0.f, 0.f, 0.f, 0.f};

#pragma unroll
    for (int nt = 0; nt < 8; nt++) {
        const unsigned short* bp = Bs + (nt * 16 + mlane) * LDR + quad * 8;
#pragma unroll
        for (int ks = 0; ks < KS; ks++) {
            bf16x8 b = *(const bf16x8*)(bp + ks * 32);
            acc[nt] = __builtin_amdgcn_mfma_f32_16x16x32_bf16(a[ks], b, acc[nt], 0, 0, 0);
        }
    }

    // C/D mapping: col = lane&15, row = quad*4 + reg
    float rv4[4] = {0.f, 0.f, 0.f, 0.f};
    if (rvec) {
#pragma unroll
        for (int r = 0; r < 4; r++) {
            int row = m0 + wv * 16 + quad * 4 + r;
            if (row < M) rv4[r] = rvec[row];
        }
    }
    float sp[8], qp[8];
#pragma unroll
    for (int nt = 0; nt < 8; nt++) {
        int colx = n0 + nt * 16 + mlane;
        float bv = bias[colx];
        float uvn = uvec ? uvec[colx] : 0.f;
        float s = 0.f, q = 0.f;
#pragma unroll
        for (int r = 0; r < 4; r++) {
            int row = m0 + wv * 16 + quad * 4 + r;
            if (row < M) {
                float h = acc[nt][r] + bv + rv4[r] * uvn;
                if (outb) outb[(size_t)row * HID + colx] = __float2bfloat16(h);
                if (outf) outf[(size_t)row * HID + colx] = h;
                s += h;
                q += h * h;
            }
        }
        sp[nt] = s;
        qp[nt] = q;
    }
    if (gsum) {
#pragma unroll
        for (int nt = 0; nt < 8; nt++) {
            sp[nt] += __shfl_xor(sp[nt], 16);
            sp[nt] += __shfl_xor(sp[nt], 32);
            qp[nt] += __shfl_xor(qp[nt], 16);
            qp[nt] += __shfl_xor(qp[nt], 32);
        }
        if (quad == 0) {
#pragma unroll
            for (int nt = 0; nt < 8; nt++) {
                sred[wv][nt * 16 + mlane] = sp[nt];
                qred[wv][nt * 16 + mlane] = qp[nt];
            }
        }
        __syncthreads();
        if (t < 128) {
            float ss = sred[0][t] + sred[1][t] + sred[2][t] + sred[3][t];
            float qq = qred[0][t] + qred[1][t] + qred[2][t] + qred[3][t];
            atomicAdd(&gsum[n0 + t], ss);
            atomicAdd(&gsq[n0 + t], qq);
        }
    }
}

extern "C" void kernel_launch(void* const* d_in, const int* in_sizes, int n_in, void* d_out,
                              int out_size, void* d_ws, size_t ws_size, hipStream_t stream) {
    const float* x = (const float*)d_in[0];
    const int* ei = (const int*)d_in[1];
    const float* W1 = (const float*)d_in[2];
    const float* b1 = (const float*)d_in[3];
    const float* g1 = (const float*)d_in[4];
    const float* be1 = (const float*)d_in[5];
    const float* W2 = (const float*)d_in[6];
    const float* b2 = (const float*)d_in[7];
    const float* g2 = (const float*)d_in[8];
    const float* be2 = (const float*)d_in[9];
    const float* Wfc = (const float*)d_in[10];
    const float* bfc = (const float*)d_in[11];
    float* out = (float*)d_out;

    const int N = in_sizes[0] / NFEAT;  // 50000
    const int E = in_sizes[1] / 2;      // 800000
    const float invN = 1.0f / (float)N;

    char* ws = (char*)d_ws;
    size_t off = 0;
    auto alloc = [&](size_t bytes) -> void* {
        void* p = ws + off;
        off += (bytes + 255) & ~(size_t)255;
        return p;
    };
    int* row_cnt = (int*)alloc((size_t)N * 4);
    int* partial = (int*)alloc((size_t)N * 4);
    int* row_start = (int*)alloc((size_t)N * 4);
    int* blk = (int*)alloc(256 * 4);
    float* dinv = (float*)alloc((size_t)N * 4);
    int* rank = (int*)alloc((size_t)E * 4);
    int* col_idx = (int*)alloc((size_t)E * 4);
    float* gs1 = (float*)alloc(512 * 4);   // gs1 | gs1+256 ; gs2 contiguous after
    float* gs2 = (float*)alloc(512 * 4);
    float* sc1 = (float*)alloc(256 * 4);
    float* bv1 = (float*)alloc(256 * 4);
    float* uvec = (float*)alloc(256 * 4);
    float* sc2 = (float*)alloc(256 * 4);
    float* of2 = (float*)alloc(256 * 4);
    float* rvec = (float*)alloc((size_t)N * 4);
    __hip_bfloat16* Wt1 = (__hip_bfloat16*)alloc(256 * 128 * 2);
    __hip_bfloat16* Wtf = (__hip_bfloat16*)alloc(256 * 256 * 2);
    __hip_bfloat16* WfT = (__hip_bfloat16*)alloc(256 * 128 * 2);
    // node buffers padded by 64 rows (GEMM A-fragment overread of last block)
    __hip_bfloat16* xs = (__hip_bfloat16*)alloc((size_t)(N + 64) * NFEAT * 2);
    __hip_bfloat16* aggX = (__hip_bfloat16*)alloc((size_t)(N + 64) * NFEAT * 2);
    __hip_bfloat16* t1s = (__hip_bfloat16*)alloc((size_t)(N + 64) * NFEAT * 2);
    __hip_bfloat16* h2 = (__hip_bfloat16*)alloc((size_t)(N + 64) * HID * 2);
    __hip_bfloat16* t2 = xs;  // xs dead after spmm1

    hipMemsetAsync(row_cnt, 0, (size_t)N * 4, stream);
    hipMemsetAsync(gs1, 0, 1024 * 4, stream);  // gs1 + gs2 (contiguous)

    // CSR build
    k_count<<<(E + 255) / 256, 256, 0, stream>>>(ei, E, row_cnt, rank);
    int nblk = (N + 255) / 256;
    k_scan1<<<nblk, 256, 0, stream>>>(row_cnt, N, partial, blk);
    k_scan2<<<1, 256, 0, stream>>>(blk, nblk);
    k_finalize<<<nblk, 256, 0, stream>>>(partial, blk, row_cnt, N, row_start, dinv);
    k_fill<<<(E + 255) / 256, 256, 0, stream>>>(ei, rank, row_start, E, col_idx);

    k_transpose2<<<384, 256, 0, stream>>>(W1, Wfc, Wt1, Wtf);

    // xs = dinv_row * x (bf16); shift = log2(128/4) = 5
    k_scale_cast<<<(N * NFEAT / 4 + 255) / 256, 256, 0, stream>>>(x, dinv, xs, 5, N * NFEAT / 4);

    int sg = (N + 3) / 4;
    k_rvec<<<sg, 256, 0, stream>>>(row_start, row_cnt, col_idx, dinv, rvec, N);

    dim3 gg((N + 63) / 64, 2);
    // t1 = A_hat * x : aggX (plain) + t1s (dinv-prescaled for pass 2)
    k_spmm_w<NFEAT><<<sg, 256, 0, stream>>>(xs, row_start, row_cnt, col_idx, dinv, aggX, t1s, N);
    // BN1 stats only: h1 = aggX@W1 + b1 (never materialized)
    k_gemm2<NFEAT><<<gg, 256, 0, stream>>>(aggX, Wt1, b1, nullptr, nullptr, gs1, gs1 + 256,
                                           nullptr, nullptr, nullptr, nullptr, N);
    k_bnfold<<<1, 256, 0, stream>>>(gs1, gs1 + 256, g1, be1, b1, invN, sc1, bv1);
    k_foldW<<<128, 256, 0, stream>>>(W1, W2, sc1, WfT);
    k_uvec<<<1, 256, 0, stream>>>(W2, bv1, uvec);
    // t2 = A_hat * t1 (128-ch aggregation replaces the old 256-ch one)
    k_spmm_w<NFEAT><<<sg, 256, 0, stream>>>(t1s, row_start, row_cnt, col_idx, dinv, t2, nullptr, N);
    // h2pre = t2 @ (W1*diag(sc1)*W2) + rvec*uvec^T + b2, fused BN2 stats
    k_gemm2<NFEAT><<<gg, 256, 0, stream>>>(t2, WfT, b2, h2, nullptr, gs2, gs2 + 256,
                                           rvec, uvec, nullptr, nullptr, N);
    k_bnfold<<<1, 256, 0, stream>>>(gs2, gs2 + 256, g2, be2, nullptr, invN, sc2, of2);
    // out = BN2(h2pre) @ Wfc + bfc ; BN2 affine folded into A-load
    k_gemm2<HID><<<gg, 256, 0, stream>>>(h2, Wtf, bfc, nullptr, out, nullptr, nullptr,
                                         nullptr, nullptr, sc2, of2, N);
}

// Round 3
// 367.642 us; speedup vs baseline: 1.4618x; 1.1039x over previous
//
#include <hip/hip_runtime.h>
#include <hip/hip_bf16.h>

#define NFEAT 128
#define HID 256
#define BN_EPS 1e-5f
#define NBIN 64  // stats replica bins (atomic de-contention)

typedef __attribute__((ext_vector_type(8))) __bf16 bf16x8;
typedef __attribute__((ext_vector_type(4))) float f32x4;

static __device__ __forceinline__ float bflo(unsigned u) {
    union { unsigned x; float f; } c; c.x = u << 16; return c.f;
}
static __device__ __forceinline__ float bfhi(unsigned u) {
    union { unsigned x; float f; } c; c.x = u & 0xffff0000u; return c.f;
}

// ---------- CSR build ----------
__global__ void k_count(const int* __restrict__ ei, int E, int* __restrict__ cnt,
                        int* __restrict__ rank) {
    int e = blockIdx.x * blockDim.x + threadIdx.x;
    if (e < E) rank[e] = atomicAdd(&cnt[ei[E + e]], 1);
}

__global__ void k_scan1(const int* __restrict__ cnt, int n, int* __restrict__ partial,
                        int* __restrict__ blk_total) {
    __shared__ int sh[256];
    int i = blockIdx.x * 256 + threadIdx.x;
    int v = (i < n) ? cnt[i] : 0;
    sh[threadIdx.x] = v;
    __syncthreads();
    for (int off = 1; off < 256; off <<= 1) {
        int x = (threadIdx.x >= off) ? sh[threadIdx.x - off] : 0;
        __syncthreads();
        sh[threadIdx.x] += x;
        __syncthreads();
    }
    if (i < n) partial[i] = sh[threadIdx.x] - v;
    if (threadIdx.x == 255) blk_total[blockIdx.x] = sh[255];
}

__global__ void k_scan2(int* __restrict__ blk, int nb) {
    __shared__ int sh[256];
    int t = threadIdx.x;
    int v = (t < nb) ? blk[t] : 0;
    sh[t] = v;
    __syncthreads();
    for (int off = 1; off < 256; off <<= 1) {
        int x = (t >= off) ? sh[t - off] : 0;
        __syncthreads();
        sh[t] += x;
        __syncthreads();
    }
    if (t < nb) blk[t] = sh[t] - v;
}

__global__ void k_finalize(const int* __restrict__ partial, const int* __restrict__ blk,
                           const int* __restrict__ cnt, int n, int* __restrict__ row_start,
                           float* __restrict__ dinv) {
    int i = blockIdx.x * blockDim.x + threadIdx.x;
    if (i < n) {
        row_start[i] = partial[i] + blk[i >> 8];
        dinv[i] = rsqrtf((float)(cnt[i] + 1));
    }
}

__global__ void k_fill(const int* __restrict__ ei, const int* __restrict__ rank,
                       const int* __restrict__ row_start, int E, int* __restrict__ col) {
    int e = blockIdx.x * blockDim.x + threadIdx.x;
    if (e < E) {
        int d = ei[E + e];
        col[row_start[d] + rank[e]] = ei[e];
    }
}

// ---------- r = A_hat * 1  (r_i = dinv_i*(dinv_i + sum_j dinv_j)) ----------
__global__ __launch_bounds__(256) void k_rvec(const int* __restrict__ rs,
                                              const int* __restrict__ rc,
                                              const int* __restrict__ col,
                                              const float* __restrict__ dinv,
                                              float* __restrict__ r, int N) {
    const int wid = blockIdx.x * 4 + (threadIdx.x >> 6);
    if (wid >= N) return;
    const int lane = threadIdx.x & 63;
    const int s = rs[wid];
    const int deg = rc[wid];
    float acc = 0.f;
    for (int e = lane; e < deg; e += 64) acc += dinv[col[s + e]];
#pragma unroll
    for (int m = 1; m < 64; m <<= 1) acc += __shfl_xor(acc, m);
    if (lane == 0) {
        float di = dinv[wid];
        r[wid] = di * (di + acc);
    }
}

// ---------- fp32 -> bf16 cast with per-row dinv scale ----------
__global__ void k_scale_cast(const float* __restrict__ in, const float* __restrict__ dinv,
                             __hip_bfloat16* __restrict__ out, int shift, int n4) {
    int i = blockIdx.x * blockDim.x + threadIdx.x;
    if (i < n4) {
        float d = dinv[i >> shift];
        float4 v = *(const float4*)(in + (size_t)i * 4);
        __hip_bfloat16* o = out + (size_t)i * 4;
        o[0] = __float2bfloat16(v.x * d);
        o[1] = __float2bfloat16(v.y * d);
        o[2] = __float2bfloat16(v.z * d);
        o[3] = __float2bfloat16(v.w * d);
    }
}

// ---------- weight transposes (W1 -> Wt1 [256][128], Wfc -> Wtf [256][256]) ----------
__global__ void k_transpose2(const float* __restrict__ W1, const float* __restrict__ Wf,
                             __hip_bfloat16* __restrict__ Wt1, __hip_bfloat16* __restrict__ Wtf) {
    int idx = blockIdx.x * 256 + threadIdx.x;
    if (idx < 32768) {
        int n = idx & 255;           // out channel
        int k = idx >> 8;            // 0..127
        Wt1[n * 128 + k] = __float2bfloat16(W1[k * 256 + n]);
    } else {
        int base = idx - 32768;      // 0..65535
        int n = base & 255;
        int k = base >> 8;           // 0..255
        Wtf[n * 256 + k] = __float2bfloat16(Wf[k * 256 + n]);
    }
}

// ---------- BN affine fold over NBIN replica bins ----------
__global__ void k_bnfold(const float* __restrict__ gs, const float* __restrict__ g,
                         const float* __restrict__ be, const float* __restrict__ b, float invN,
                         float* __restrict__ sc, float* __restrict__ bv) {
    int c = threadIdx.x;
    float s = 0.f, q = 0.f;
    for (int r = 0; r < NBIN; r++) {
        s += gs[r * 512 + c];
        q += gs[r * 512 + 256 + c];
    }
    float mean = s * invN;
    float var = q * invN - mean * mean;
    float scl = rsqrtf(var + BN_EPS) * g[c];
    float bb = b ? b[c] : 0.f;
    sc[c] = scl;
    bv[c] = (bb - mean) * scl + be[c];
}

// ---------- folded weight: WfT[n][k] = sum_m W1[k][m]*sc[m]*W2[m][n]  (Bt layout, bf16) ----------
__global__ __launch_bounds__(256) void k_foldW(const float* __restrict__ W1,
                                               const float* __restrict__ W2,
                                               const float* __restrict__ sc,
                                               __hip_bfloat16* __restrict__ WfT) {
    int k = blockIdx.x;    // 0..127
    int n = threadIdx.x;   // 0..255
    float acc = 0.f;
    for (int m = 0; m < 256; m++) acc += W1[k * 256 + m] * sc[m] * W2[m * 256 + n];
    WfT[(size_t)n * 128 + k] = __float2bfloat16(acc);
}

// ---------- u[n] = sum_m W2[m][n] * bv[m] ----------
__global__ void k_uvec(const float* __restrict__ W2, const float* __restrict__ bv,
                       float* __restrict__ u) {
    int n = threadIdx.x;
    float acc = 0.f;
    for (int m = 0; m < 256; m++) acc += W2[m * 256 + n] * bv[m];
    u[n] = acc;
}

// ---------- wave-per-node pure-add SpMM on pre-scaled rows ----------
template <int PL>
static __device__ __forceinline__ void loadrow(const __hip_bfloat16* p, float* v) {
    if constexpr (PL == 4) {
        uint2 u = *(const uint2*)p;
        v[0] = bflo(u.x); v[1] = bfhi(u.x); v[2] = bflo(u.y); v[3] = bfhi(u.y);
    } else {
        unsigned u = *(const unsigned*)p;
        v[0] = bflo(u); v[1] = bfhi(u);
    }
}

template <int C>
__global__ __launch_bounds__(256) void k_spmm_w(const __hip_bfloat16* __restrict__ Hs,
                                                const int* __restrict__ rs,
                                                const int* __restrict__ rc,
                                                const int* __restrict__ col,
                                                const float* __restrict__ dinv,
                                                __hip_bfloat16* __restrict__ out,
                                                __hip_bfloat16* __restrict__ out2, int N) {
    constexpr int PL = C / 64;
    const int wid = blockIdx.x * 4 + (threadIdx.x >> 6);
    if (wid >= N) return;
    const int lane = threadIdx.x & 63;
    const int ch = lane * PL;
    const int s = rs[wid];
    const int deg = rc[wid];
    const float di = dinv[wid];

    float acc[PL];
    loadrow<PL>(Hs + (size_t)wid * C + ch, acc);  // self-loop term

    int e = 0;
    for (; e + 8 <= deg; e += 8) {
        int idx[8];
#pragma unroll
        for (int j = 0; j < 8; j++) idx[j] = col[s + e + j];
        float v[8][PL];
#pragma unroll
        for (int j = 0; j < 8; j++) loadrow<PL>(Hs + (size_t)idx[j] * C + ch, v[j]);
#pragma unroll
        for (int j = 0; j < 8; j++)
#pragma unroll
            for (int i = 0; i < PL; i++) acc[i] += v[j][i];
    }
    for (; e < deg; e++) {
        int i0 = col[s + e];
        float v0[PL];
        loadrow<PL>(Hs + (size_t)i0 * C + ch, v0);
#pragma unroll
        for (int i = 0; i < PL; i++) acc[i] += v0[i];
    }
    union { unsigned u[PL / 2]; unsigned short us[PL]; } o;
#pragma unroll
    for (int i = 0; i < PL; i++) {
        __hip_bfloat16 b = __float2bfloat16(di * acc[i]);
        o.us[i] = *(unsigned short*)&b;
    }
    if constexpr (PL == 4)
        *(uint2*)(out + (size_t)wid * C + ch) = *(uint2*)o.u;
    else
        *(unsigned*)(out + (size_t)wid * C + ch) = o.u[0];
    if (out2) {  // dinv-prescaled copy for the next aggregation pass
        union { unsigned u[PL / 2]; unsigned short us[PL]; } o2;
        float d2 = di * di;
#pragma unroll
        for (int i = 0; i < PL; i++) {
            __hip_bfloat16 b = __float2bfloat16(d2 * acc[i]);
            o2.us[i] = *(unsigned short*)&b;
        }
        if constexpr (PL == 4)
            *(uint2*)(out2 + (size_t)wid * C + ch) = *(uint2*)o2.u;
        else
            *(unsigned*)(out2 + (size_t)wid * C + ch) = o2.u[0];
    }
}

// ---------- single-barrier MFMA GEMM ----------
// out[M][256] = A[M][K] @ B[K][256] (+bias) (+ rank-1 rvec*uvec^T) ; optional BN affine on A;
// optional bf16/fp32 out; optional fused BN stats (atomics into NBIN replica bins).
// Block = 64 rows x 128 cols, grid (M/64, 2).
// NOTE: last block reads A rows >= M (buffers padded; results discarded by store guard).
template <int K>
__global__ __launch_bounds__(256) void k_gemm2(const __hip_bfloat16* __restrict__ A,
                                               const __hip_bfloat16* __restrict__ Bt,
                                               const float* __restrict__ bias,
                                               __hip_bfloat16* __restrict__ outb,
                                               float* __restrict__ outf,
                                               float* __restrict__ gs,
                                               const float* __restrict__ rvec,
                                               const float* __restrict__ uvec,
                                               const float* __restrict__ bnsc,
                                               const float* __restrict__ bnof, int M) {
    constexpr int KS = K / 32;       // MFMA k-steps
    constexpr int LDR = K + 8;       // LDS row stride (elems): +16B pad -> <=2-way read alias
    constexpr int ROWU4 = K / 8;     // uint4 per B row
    __shared__ __align__(16) unsigned short Bs[128 * LDR];
    __shared__ float sred[4][128];
    __shared__ float qred[4][128];

    const int t = threadIdx.x;
    const int wv = t >> 6;
    const int lane = t & 63;
    const int mlane = lane & 15;
    const int quad = lane >> 4;
    const int m0 = blockIdx.x * 64;
    const int n0 = blockIdx.y * 128;

    // A fragments: wave wv covers rows m0+wv*16 .. +15; lane's operand row = m0+wv*16+mlane
    const int arow = m0 + wv * 16 + mlane;
    bf16x8 a[KS];
#pragma unroll
    for (int ks = 0; ks < KS; ks++) {
        bf16x8 raw = *(const bf16x8*)(A + (size_t)arow * K + ks * 32 + quad * 8);
        if (bnsc) {  // BN affine applied in-register (pre-MFMA), channel = ks*32+quad*8+j
            int cb = ks * 32 + quad * 8;
            union { bf16x8 v; unsigned u[4]; } cu; cu.v = raw;
            union { unsigned u[4]; unsigned short us[8]; } ou;
#pragma unroll
            for (int j = 0; j < 4; j++) {
                float lo = bflo(cu.u[j]) * bnsc[cb + 2 * j] + bnof[cb + 2 * j];
                float hi = bfhi(cu.u[j]) * bnsc[cb + 2 * j + 1] + bnof[cb + 2 * j + 1];
                __hip_bfloat16 bl = __float2bfloat16(lo);
                __hip_bfloat16 bh = __float2bfloat16(hi);
                ou.us[2 * j] = *(unsigned short*)&bl;
                ou.us[2 * j + 1] = *(unsigned short*)&bh;
            }
            a[ks] = *(bf16x8*)ou.u;
        } else {
            a[ks] = raw;
        }
    }

    // stage B slice: Bt[n0..n0+128][0..K] -> Bs (coalesced, all 16B loads in flight)
#pragma unroll
    for (int i = 0; i < 128 * ROWU4 / 256; i++) {
        int idx = t + i * 256;
        int row = idx / ROWU4;
        int c = idx % ROWU4;
        uint4 v = *(const uint4*)(Bt + (size_t)(n0 + row) * K + c * 8);
        *(uint4*)(Bs + row * LDR + c * 8) = v;
    }
    __syncthreads();  // the ONLY barrier before the epilogue

    f32x4 acc[8];
#pragma unroll
    for (int i = 0; i < 8; i++) acc[i] = (f32x4){0.f, 0.f, 0.f, 0.f};

#pragma unroll
    for (int nt = 0; nt < 8; nt++) {
        const unsigned short* bp = Bs + (nt * 16 + mlane) * LDR + quad * 8;
#pragma unroll
        for (int ks = 0; ks < KS; ks++) {
            bf16x8 b = *(const bf16x8*)(bp + ks * 32);
            acc[nt] = __builtin_amdgcn_mfma_f32_16x16x32_bf16(a[ks], b, acc[nt], 0, 0, 0);
        }
    }

    // C/D mapping: col = lane&15, row = quad*4 + reg
    float rv4[4] = {0.f, 0.f, 0.f, 0.f};
    if (rvec) {
#pragma unroll
        for (int r = 0; r < 4; r++) {
            int row = m0 + wv * 16 + quad * 4 + r;
            if (row < M) rv4[r] = rvec[row];
        }
    }
    float sp[8], qp[8];
#pragma unroll
    for (int nt = 0; nt < 8; nt++) {
        int colx = n0 + nt * 16 + mlane;
        float bv = bias[colx];
        float uvn = uvec ? uvec[colx] : 0.f;
        float s = 0.f, q = 0.f;
#pragma unroll
        for (int r = 0; r < 4; r++) {
            int row = m0 + wv * 16 + quad * 4 + r;
            if (row < M) {
                float h = acc[nt][r] + bv + rv4[r] * uvn;
                if (outb) outb[(size_t)row * HID + colx] = __float2bfloat16(h);
                if (outf) outf[(size_t)row * HID + colx] = h;
                s += h;
                q += h * h;
            }
        }
        sp[nt] = s;
        qp[nt] = q;
    }
    if (gs) {
#pragma unroll
        for (int nt = 0; nt < 8; nt++) {
            sp[nt] += __shfl_xor(sp[nt], 16);
            sp[nt] += __shfl_xor(sp[nt], 32);
            qp[nt] += __shfl_xor(qp[nt], 16);
            qp[nt] += __shfl_xor(qp[nt], 32);
        }
        if (quad == 0) {
#pragma unroll
            for (int nt = 0; nt < 8; nt++) {
                sred[wv][nt * 16 + mlane] = sp[nt];
                qred[wv][nt * 16 + mlane] = qp[nt];
            }
        }
        __syncthreads();
        if (t < 128) {
            float ss = sred[0][t] + sred[1][t] + sred[2][t] + sred[3][t];
            float qq = qred[0][t] + qred[1][t] + qred[2][t] + qred[3][t];
            float* bin = gs + (blockIdx.x & (NBIN - 1)) * 512;  // de-contended replicas
            atomicAdd(&bin[n0 + t], ss);
            atomicAdd(&bin[256 + n0 + t], qq);
        }
    }
}

extern "C" void kernel_launch(void* const* d_in, const int* in_sizes, int n_in, void* d_out,
                              int out_size, void* d_ws, size_t ws_size, hipStream_t stream) {
    const float* x = (const float*)d_in[0];
    const int* ei = (const int*)d_in[1];
    const float* W1 = (const float*)d_in[2];
    const float* b1 = (const float*)d_in[3];
    const float* g1 = (const float*)d_in[4];
    const float* be1 = (const float*)d_in[5];
    const float* W2 = (const float*)d_in[6];
    const float* b2 = (const float*)d_in[7];
    const float* g2 = (const float*)d_in[8];
    const float* be2 = (const float*)d_in[9];
    const float* Wfc = (const float*)d_in[10];
    const float* bfc = (const float*)d_in[11];
    float* out = (float*)d_out;

    const int N = in_sizes[0] / NFEAT;  // 50000
    const int E = in_sizes[1] / 2;      // 800000
    const float invN = 1.0f / (float)N;

    char* ws = (char*)d_ws;
    size_t off = 0;
    auto alloc = [&](size_t bytes) -> void* {
        void* p = ws + off;
        off += (bytes + 255) & ~(size_t)255;
        return p;
    };
    int* row_cnt = (int*)alloc((size_t)N * 4);
    int* partial = (int*)alloc((size_t)N * 4);
    int* row_start = (int*)alloc((size_t)N * 4);
    int* blk = (int*)alloc(256 * 4);
    float* dinv = (float*)alloc((size_t)N * 4);
    int* rank = (int*)alloc((size_t)E * 4);
    int* col_idx = (int*)alloc((size_t)E * 4);
    float* gs1 = (float*)alloc((size_t)NBIN * 512 * 4);  // gs2 contiguous after
    float* gs2 = (float*)alloc((size_t)NBIN * 512 * 4);
    float* sc1 = (float*)alloc(256 * 4);
    float* bv1 = (float*)alloc(256 * 4);
    float* uvec = (float*)alloc(256 * 4);
    float* sc2 = (float*)alloc(256 * 4);
    float* of2 = (float*)alloc(256 * 4);
    float* rvec = (float*)alloc((size_t)N * 4);
    __hip_bfloat16* Wt1 = (__hip_bfloat16*)alloc(256 * 128 * 2);
    __hip_bfloat16* Wtf = (__hip_bfloat16*)alloc(256 * 256 * 2);
    __hip_bfloat16* WfT = (__hip_bfloat16*)alloc(256 * 128 * 2);
    // node buffers padded by 64 rows (GEMM A-fragment overread of last block)
    __hip_bfloat16* xs = (__hip_bfloat16*)alloc((size_t)(N + 64) * NFEAT * 2);
    __hip_bfloat16* aggX = (__hip_bfloat16*)alloc((size_t)(N + 64) * NFEAT * 2);
    __hip_bfloat16* t1s = (__hip_bfloat16*)alloc((size_t)(N + 64) * NFEAT * 2);
    __hip_bfloat16* h2 = (__hip_bfloat16*)alloc((size_t)(N + 64) * HID * 2);
    __hip_bfloat16* t2 = xs;  // xs dead after spmm1

    hipMemsetAsync(row_cnt, 0, (size_t)N * 4, stream);
    hipMemsetAsync(gs1, 0, (size_t)NBIN * 512 * 4 * 2, stream);  // gs1 + gs2 (contiguous)

    // CSR build
    k_count<<<(E + 255) / 256, 256, 0, stream>>>(ei, E, row_cnt, rank);
    int nblk = (N + 255) / 256;
    k_scan1<<<nblk, 256, 0, stream>>>(row_cnt, N, partial, blk);
    k_scan2<<<1, 256, 0, stream>>>(blk, nblk);
    k_finalize<<<nblk, 256, 0, stream>>>(partial, blk, row_cnt, N, row_start, dinv);
    k_fill<<<(E + 255) / 256, 256, 0, stream>>>(ei, rank, row_start, E, col_idx);

    k_transpose2<<<384, 256, 0, stream>>>(W1, Wfc, Wt1, Wtf);

    // xs = dinv_row * x (bf16); shift = log2(128/4) = 5
    k_scale_cast<<<(N * NFEAT / 4 + 255) / 256, 256, 0, stream>>>(x, dinv, xs, 5, N * NFEAT / 4);

    int sg = (N + 3) / 4;
    k_rvec<<<sg, 256, 0, stream>>>(row_start, row_cnt, col_idx, dinv, rvec, N);

    dim3 gg((N + 63) / 64, 2);
    // t1 = A_hat * x : aggX (plain) + t1s (dinv-prescaled for pass 2)
    k_spmm_w<NFEAT><<<sg, 256, 0, stream>>>(xs, row_start, row_cnt, col_idx, dinv, aggX, t1s, N);
    // BN1 stats only: h1 = aggX@W1 + b1 (never materialized)
    k_gemm2<NFEAT><<<gg, 256, 0, stream>>>(aggX, Wt1, b1, nullptr, nullptr, gs1,
                                           nullptr, nullptr, nullptr, nullptr, N);
    k_bnfold<<<1, 256, 0, stream>>>(gs1, g1, be1, b1, invN, sc1, bv1);
    k_foldW<<<128, 256, 0, stream>>>(W1, W2, sc1, WfT);
    k_uvec<<<1, 256, 0, stream>>>(W2, bv1, uvec);
    // t2 = A_hat * t1 (128-ch aggregation replaces the old 256-ch one)
    k_spmm_w<NFEAT><<<sg, 256, 0, stream>>>(t1s, row_start, row_cnt, col_idx, dinv, t2, nullptr, N);
    // h2pre = t2 @ (W1*diag(sc1)*W2) + rvec*uvec^T + b2, fused BN2 stats
    k_gemm2<NFEAT><<<gg, 256, 0, stream>>>(t2, WfT, b2, h2, nullptr, gs2,
                                           rvec, uvec, nullptr, nullptr, N);
    k_bnfold<<<1, 256, 0, stream>>>(gs2, g2, be2, nullptr, invN, sc2, of2);
    // out = BN2(h2pre) @ Wfc + bfc ; BN2 affine folded into A-load
    k_gemm2<HID><<<gg, 256, 0, stream>>>(h2, Wtf, bfc, nullptr, out, nullptr,
                                         nullptr, nullptr, sc2, of2, N);
}